// Round 8
// baseline (186.091 us; speedup 1.0000x reference)
//
#include <hip/hip_runtime.h>
#include <math.h>

typedef __attribute__((ext_vector_type(8))) short short8;
typedef __attribute__((ext_vector_type(4))) short short4v;
typedef __attribute__((ext_vector_type(4))) float f32x4;

constexpr int BLOCK = 512;
constexpr int B_ = 4, C_ = 64, N_ = 32768, K_ = 16;
constexpr int P_ = 16;            // points per block -> 48 cols (col = k*16 + p)
constexpr int NCOL = 48;
constexpr int NFRAG = 48;         // 24 (L1: 8m x 3ks) + 16 (L2: 4m x 4ks) + 8 (L3: 4m x 2ks)

// fragment-linear LDS layouts: buf[frag_row][col][8], frag_row = ks*4 + quad
// addr_shorts = (fr*NCOL + col)*8 + pos ; ci = fr*8 + pos
constexpr int XFR  = 12;          // x:  ks 0..2 (ci pad 68->96)
constexpr int H1FR = 16;          // h1: ks 0..3 (128 ci)
constexpr int H2FR = 8;           // h2: ks 0..1 (64 ci)

// round-to-nearest-even split: f = hi_bf16 + lo_bf16 (+O(2^-17 rel))
__device__ __forceinline__ void bf16split(float f, short &hi, short &lo) {
    unsigned u  = __builtin_bit_cast(unsigned, f);
    unsigned hb = (u + 0x7FFFu + ((u >> 16) & 1u)) & 0xFFFF0000u;
    float hf    = __builtin_bit_cast(float, hb);
    hi = (short)(hb >> 16);
    float lf    = f - hf;                       // exact
    unsigned ul = __builtin_bit_cast(unsigned, lf);
    lo = (short)((ul + 0x7FFFu + ((ul >> 16) & 1u)) >> 16);
}

__device__ __forceinline__ f32x4 mm(short8 a, short8 b, f32x4 c) {
    return __builtin_amdgcn_mfma_f32_16x16x32_bf16(a, b, c, 0, 0, 0);
}

// ---------------- prologue: BN-fold + split weights into A-fragment layout ----
__global__ void prep_wfrags(const float* __restrict__ W1, const float* __restrict__ g1,
                            const float* __restrict__ W2, const float* __restrict__ g2,
                            const float* __restrict__ W3, const float* __restrict__ g3,
                            unsigned short* __restrict__ wf)
{
    const int gid = blockIdx.x * 256 + threadIdx.x;   // [0, 3072)
    if (gid >= NFRAG * 64) return;
    const int f = gid >> 6, l = gid & 63;
    const float RS = 1.0f / sqrtf(1.0f + 1e-5f);
    const float *W, *g; int CI, m, ks;
    if (f < 24)      { W = W1; g = g1; CI = 68;  m = f / 3;        ks = f % 3; }
    else if (f < 40) { W = W2; g = g2; CI = 128; m = (f - 24) / 4; ks = (f - 24) % 4; }
    else             { W = W3; g = g3; CI = 64;  m = (f - 40) / 2; ks = (f - 40) % 2; }
    const int co = m * 16 + (l & 15);
    const int kb = ks * 32 + ((l >> 4) << 3);
    const float gs = g[co] * RS;
    short8 h8, l8;
#pragma unroll
    for (int j = 0; j < 8; ++j) {
        const int k = kb + j;
        const float w = (k < CI) ? W[(size_t)co * CI + k] * gs : 0.0f;
        short hi, lo; bf16split(w, hi, lo);
        h8[j] = hi; l8[j] = lo;
    }
    *reinterpret_cast<short8*>(wf + (size_t)(f * 128 + l) * 8)      = h8;
    *reinterpret_cast<short8*>(wf + (size_t)(f * 128 + 64 + l) * 8) = l8;
}

__device__ __forceinline__ void ldfrag(const unsigned short* __restrict__ wf,
                                       int f, int l, short8 &h, short8 &lo) {
    h  = *reinterpret_cast<const short8*>(wf + (size_t)(f * 128 + l) * 8);
    lo = *reinterpret_cast<const short8*>(wf + (size_t)(f * 128 + 64 + l) * 8);
}

__global__ __launch_bounds__(BLOCK, 4)
void mvp_mfma(const float* __restrict__ src, const float* __restrict__ tgt,
              const float* __restrict__ feat,
              const unsigned short* __restrict__ wf,
              const float* __restrict__ b1, const float* __restrict__ g1, const float* __restrict__ be1,
              const float* __restrict__ b2, const float* __restrict__ g2, const float* __restrict__ be2,
              const float* __restrict__ b3, const float* __restrict__ g3, const float* __restrict__ be3,
              float* __restrict__ out)
{
    __shared__ __align__(16) unsigned short xa_hi[XFR*NCOL*8],  xa_lo[XFR*NCOL*8];   // 9 KB x2
    __shared__ __align__(16) unsigned short h1_hi[H1FR*NCOL*8], h1_lo[H1FR*NCOL*8];  // 12 KB x2
    __shared__ __align__(16) unsigned short h2_hi[H2FR*NCOL*8], h2_lo[H2FR*NCOL*8];  // 6 KB x2
    __shared__ float bias1[128], bias2[64], bias3[64];
    // total ~55 KB -> 2 blocks/CU

    const int tid = threadIdx.x;
    const int w   = tid >> 6;                    // 8 waves
    const int l   = tid & 63;
    const int b   = blockIdx.x >> 11;            // N_/P_ = 2048 blocks per batch
    const int n0  = (blockIdx.x & 2047) * P_;
    const float RS = 1.0f / sqrtf(1.0f + 1e-5f);

    // ================= staging =================
    // zero x pad: fr 9..11 fully (b128), fr 8 pos 4..7 (b64)
    if (tid < 144) {
        const int o = 9*NCOL*8 + tid*8;
        *reinterpret_cast<short8*>(&xa_hi[o]) = short8{0,0,0,0,0,0,0,0};
        *reinterpret_cast<short8*>(&xa_lo[o]) = short8{0,0,0,0,0,0,0,0};
    } else if (tid < 192) {
        const int o = (8*NCOL + (tid - 144))*8 + 4;
        *reinterpret_cast<short4v*>(&xa_hi[o]) = short4v{0,0,0,0};
        *reinterpret_cast<short4v*>(&xa_lo[o]) = short4v{0,0,0,0};
    }
    // feature -> ci 0..63: fr = c>>3, pos = c&7
    for (int idx = tid; idx < C_ * P_; idx += BLOCK) {
        const int c = idx >> 4, p = idx & 15;
        const float4 f = *reinterpret_cast<const float4*>(
            feat + ((size_t)(b*C_ + c) * N_ + (n0 + p)) * K_);
        const float v[3] = {f.x, f.y, f.z};
        const int fr = c >> 3, pos = c & 7;
#pragma unroll
        for (int k = 0; k < 3; ++k) {
            short hi, lo; bf16split(v[k], hi, lo);
            const int off = (fr*NCOL + k*16 + p)*8 + pos;
            xa_hi[off] = (unsigned short)hi; xa_lo[off] = (unsigned short)lo;
        }
    }
    // relation -> ci 64..67: fr = 8, pos = 0..3
    if (tid < NCOL) {
        const int p = tid & 15, k = tid >> 4;
        const int n = n0 + p;
        float d[4];
        d[0] = src[((size_t)(b*3+0)*N_ + n)*K_ + k] - tgt[(size_t)(b*3+0)*N_ + n];
        d[1] = src[((size_t)(b*3+1)*N_ + n)*K_ + k] - tgt[(size_t)(b*3+1)*N_ + n];
        d[2] = src[((size_t)(b*3+2)*N_ + n)*K_ + k] - tgt[(size_t)(b*3+2)*N_ + n];
        d[3] = d[0]*d[0] + d[1]*d[1] + d[2]*d[2];
        const int base = (8*NCOL + k*16 + p)*8;
#pragma unroll
        for (int j = 0; j < 4; ++j) {
            short hi, lo; bf16split(d[j], hi, lo);
            xa_hi[base + j] = (unsigned short)hi;
            xa_lo[base + j] = (unsigned short)lo;
        }
    }
    if (tid >= 256 && tid < 384) { int c = tid - 256; bias1[c] = b1[c]*(g1[c]*RS) + be1[c]; }
    if (tid >= 384 && tid < 448) { int c = tid - 384; bias2[c] = b2[c]*(g2[c]*RS) + be2[c]; }
    if (tid >= 448 && tid < 512) { int c = tid - 448; bias3[c] = b3[c]*(g3[c]*RS) + be3[c]; }
    __syncthreads();

    const int lq = l >> 4;          // quadrant 0..3
    const int lr = l & 15;
    const int rq = lq << 2;         // C/D row offset

    // B-frag read addr (shorts): ((ks*4 + lq)*NCOL + col)*8  — conflict-free b128
    // D-write: co = m*16 + rq + r -> fr = (co>>3) = m*2 + (lq>>1), pos = (lq&1)*4 + r

    // ================= L1: 68 -> 128 (wave = m-tile, 3 n-tiles) =========
    {
        const int m = w;
        short8 ah[3], al[3];
#pragma unroll
        for (int ks = 0; ks < 3; ++ks) ldfrag(wf, m*3 + ks, l, ah[ks], al[ks]);
        f32x4 acc[3] = {f32x4{0,0,0,0}, f32x4{0,0,0,0}, f32x4{0,0,0,0}};
#pragma unroll
        for (int ks = 0; ks < 3; ++ks) {
#pragma unroll
            for (int t = 0; t < 3; ++t) {
                const int so = ((ks*4 + lq)*NCOL + t*16 + lr)*8;
                const short8 bh = *reinterpret_cast<const short8*>(&xa_hi[so]);
                const short8 bl = *reinterpret_cast<const short8*>(&xa_lo[so]);
                acc[t] = mm(ah[ks], bh, acc[t]);
                acc[t] = mm(al[ks], bh, acc[t]);
                acc[t] = mm(ah[ks], bl, acc[t]);
            }
        }
        const int co0 = m*16 + rq;
        const float4 bb = *reinterpret_cast<const float4*>(&bias1[co0]);
        const float bbv[4] = {bb.x, bb.y, bb.z, bb.w};
        const int fr = m*2 + (lq >> 1), po = (lq & 1)*4;
#pragma unroll
        for (int t = 0; t < 3; ++t) {
            short4v h4, l4;
#pragma unroll
            for (int r = 0; r < 4; ++r) {
                const float v = fmaxf(acc[t][r] + bbv[r], 0.0f);
                short hi, lo; bf16split(v, hi, lo);
                h4[r] = hi; l4[r] = lo;
            }
            const int so = (fr*NCOL + t*16 + lr)*8 + po;
            *reinterpret_cast<short4v*>(&h1_hi[so]) = h4;
            *reinterpret_cast<short4v*>(&h1_lo[so]) = l4;
        }
    }
    __syncthreads();

    // ================= L2: 128 -> 64 (12 tiles over 8 waves) =================
    {
#pragma unroll
        for (int tt = 0; tt < 2; ++tt) {
            const int t = w + tt*8;
            if (t < 12) {
                const int m = t / 3, n = t % 3;
                f32x4 acc = {0,0,0,0};
#pragma unroll
                for (int ks = 0; ks < 4; ++ks) {
                    short8 ah, al;
                    ldfrag(wf, 24 + m*4 + ks, l, ah, al);
                    const int so = ((ks*4 + lq)*NCOL + n*16 + lr)*8;
                    const short8 bh = *reinterpret_cast<const short8*>(&h1_hi[so]);
                    const short8 bl = *reinterpret_cast<const short8*>(&h1_lo[so]);
                    acc = mm(ah, bh, acc);
                    acc = mm(al, bh, acc);
                    acc = mm(ah, bl, acc);
                }
                const int co0 = m*16 + rq;
                const float4 bb = *reinterpret_cast<const float4*>(&bias2[co0]);
                const float bbv[4] = {bb.x, bb.y, bb.z, bb.w};
                short4v h4, l4;
#pragma unroll
                for (int r = 0; r < 4; ++r) {
                    const float v = fmaxf(acc[r] + bbv[r], 0.0f);
                    short hi, lo; bf16split(v, hi, lo);
                    h4[r] = hi; l4[r] = lo;
                }
                const int so = ((m*2 + (lq >> 1))*NCOL + n*16 + lr)*8 + (lq & 1)*4;
                *reinterpret_cast<short4v*>(&h2_hi[so]) = h4;
                *reinterpret_cast<short4v*>(&h2_lo[so]) = l4;
            }
        }
    }
    __syncthreads();

    // ================= L3: 64 -> 64, relu + neighbor-sum + store ==============
    if (w < 4) {
        const int m = w;
        short8 ah[2], al[2];
#pragma unroll
        for (int ks = 0; ks < 2; ++ks) ldfrag(wf, 40 + m*2 + ks, l, ah[ks], al[ks]);
        f32x4 acc[3] = {f32x4{0,0,0,0}, f32x4{0,0,0,0}, f32x4{0,0,0,0}};
#pragma unroll
        for (int ks = 0; ks < 2; ++ks) {
#pragma unroll
            for (int t = 0; t < 3; ++t) {          // t = neighbor k; col = k*16 + p
                const int so = ((ks*4 + lq)*NCOL + t*16 + lr)*8;
                const short8 bh = *reinterpret_cast<const short8*>(&h2_hi[so]);
                const short8 bl = *reinterpret_cast<const short8*>(&h2_lo[so]);
                acc[t] = mm(ah[ks], bh, acc[t]);
                acc[t] = mm(al[ks], bh, acc[t]);
                acc[t] = mm(ah[ks], bl, acc[t]);
            }
        }
        const int co0 = m*16 + rq;
        const float4 bb = *reinterpret_cast<const float4*>(&bias3[co0]);
        const float bbv[4] = {bb.x, bb.y, bb.z, bb.w};
#pragma unroll
        for (int r = 0; r < 4; ++r) {
            float s = 0.0f;
#pragma unroll
            for (int t = 0; t < 3; ++t) s += fmaxf(acc[t][r] + bbv[r], 0.0f);
            out[(size_t)(b*64 + co0 + r) * N_ + n0 + lr] = s;
        }
    }
}

extern "C" void kernel_launch(void* const* d_in, const int* in_sizes, int n_in,
                              void* d_out, int out_size, void* d_ws, size_t ws_size,
                              hipStream_t stream) {
    const float* src  = (const float*)d_in[0];
    const float* tgt  = (const float*)d_in[1];
    const float* feat = (const float*)d_in[2];
    const float* W1 = (const float*)d_in[3];
    const float* b1 = (const float*)d_in[4];
    const float* g1 = (const float*)d_in[5];
    const float* be1= (const float*)d_in[6];
    const float* W2 = (const float*)d_in[7];
    const float* b2 = (const float*)d_in[8];
    const float* g2 = (const float*)d_in[9];
    const float* be2= (const float*)d_in[10];
    const float* W3 = (const float*)d_in[11];
    const float* b3 = (const float*)d_in[12];
    const float* g3 = (const float*)d_in[13];
    const float* be3= (const float*)d_in[14];
    float* out = (float*)d_out;
    unsigned short* wfrag = (unsigned short*)d_ws;   // 96 KB

    prep_wfrags<<<(NFRAG*64 + 255)/256, 256, 0, stream>>>(W1, g1, W2, g2, W3, g3, wfrag);

    const int grid = B_ * (N_ / P_);  // 8192 blocks, 2 resident per CU
    mvp_mfma<<<grid, BLOCK, 0, stream>>>(src, tgt, feat, wfrag,
                                         b1, g1, be1, b2, g2, be2, b3, g3, be3, out);
}

// Round 9
// 159.626 us; speedup vs baseline: 1.1658x; 1.1658x over previous
//
#include <hip/hip_runtime.h>
#include <math.h>

typedef __attribute__((ext_vector_type(8))) short short8;
typedef __attribute__((ext_vector_type(4))) short short4v;
typedef __attribute__((ext_vector_type(4))) float f32x4;
typedef __attribute__((ext_vector_type(16))) float f32x16;

constexpr int BLOCK = 512;
constexpr int B_ = 4, C_ = 64, N_ = 32768, K_ = 16;
constexpr int P_ = 32;            // points per block -> 96 cols (col = k*32 + p)
constexpr int NCOL = 96;
// wf layout: 36 32-shape frags (L1: 4m x 5ks = 20, L2: 2m x 8ks = 16),
// then 8 16-shape frags (L3: 4m x 2ks), then 256 folded-bias floats.
constexpr int NF32 = 36, NF16 = 8;
constexpr int BIAS_OFF = (NF32 + NF16) * 1024;   // in shorts

// LDS (shorts): x = [10 fr][96 col][8] stride 768/fr ; h1 = [16 fr][96][8]
// h2 aliased onto x with skewed fr-stride 776 (bank-balances 16x16 reads)
constexpr int H2STR = 776;

// round-to-nearest-even split: f = hi_bf16 + lo_bf16 (+O(2^-17 rel))
__device__ __forceinline__ void bf16split(float f, short &hi, short &lo) {
    unsigned u  = __builtin_bit_cast(unsigned, f);
    unsigned hb = (u + 0x7FFFu + ((u >> 16) & 1u)) & 0xFFFF0000u;
    float hf    = __builtin_bit_cast(float, hb);
    hi = (short)(hb >> 16);
    float lf    = f - hf;                       // exact
    unsigned ul = __builtin_bit_cast(unsigned, lf);
    lo = (short)((ul + 0x7FFFu + ((ul >> 16) & 1u)) >> 16);
}

__device__ __forceinline__ f32x4 mm16(short8 a, short8 b, f32x4 c) {
    return __builtin_amdgcn_mfma_f32_16x16x32_bf16(a, b, c, 0, 0, 0);
}
__device__ __forceinline__ f32x16 mm32(short8 a, short8 b, f32x16 c) {
    return __builtin_amdgcn_mfma_f32_32x32x16_bf16(a, b, c, 0, 0, 0);
}

// ---------------- prologue: BN-fold + split weights + fold biases ----------
__global__ void prep_wfrags(const float* __restrict__ W1, const float* __restrict__ g1,
                            const float* __restrict__ b1, const float* __restrict__ be1,
                            const float* __restrict__ W2, const float* __restrict__ g2,
                            const float* __restrict__ b2, const float* __restrict__ be2,
                            const float* __restrict__ W3, const float* __restrict__ g3,
                            const float* __restrict__ b3, const float* __restrict__ be3,
                            unsigned short* __restrict__ wf)
{
    const int gid = blockIdx.x * 256 + threadIdx.x;
    const float RS = 1.0f / sqrtf(1.0f + 1e-5f);
    const int NT = (NF32 + NF16) * 64;           // 2816 fragment lanes
    if (gid < NT) {
        const int f = gid >> 6, l = gid & 63;
        const float *W, *g; int CI, co, kb;
        if (f < 20)      { W = W1; g = g1; CI = 68;
                           co = (f / 5) * 32 + (l & 31);        kb = (f % 5) * 16 + (l >> 5) * 8; }
        else if (f < 36) { W = W2; g = g2; CI = 128;
                           co = ((f - 20) / 8) * 32 + (l & 31); kb = ((f - 20) % 8) * 16 + (l >> 5) * 8; }
        else             { W = W3; g = g3; CI = 64;
                           co = ((f - 36) / 2) * 16 + (l & 15); kb = ((f - 36) % 2) * 32 + (l >> 4) * 8; }
        const float gs = g[co] * RS;
        short8 h8, l8;
#pragma unroll
        for (int j = 0; j < 8; ++j) {
            const int k = kb + j;
            const float w = (k < CI) ? W[(size_t)co * CI + k] * gs : 0.0f;
            short hi, lo; bf16split(w, hi, lo);
            h8[j] = hi; l8[j] = lo;
        }
        *reinterpret_cast<short8*>(wf + (size_t)f * 1024 + l * 8)       = h8;
        *reinterpret_cast<short8*>(wf + (size_t)f * 1024 + 512 + l * 8) = l8;
    } else if (gid < NT + 256) {
        const int c = gid - NT;
        float* fb = reinterpret_cast<float*>(wf + BIAS_OFF);
        if (c < 128)      fb[c] = b1[c] * (g1[c] * RS) + be1[c];
        else if (c < 192) { const int q = c - 128; fb[c] = b2[q] * (g2[q] * RS) + be2[q]; }
        else              { const int q = c - 192; fb[c] = b3[q] * (g3[q] * RS) + be3[q]; }
    }
}

__device__ __forceinline__ void ldfrag(const unsigned short* __restrict__ wf,
                                       int f, int l, short8 &h, short8 &lo) {
    h  = *reinterpret_cast<const short8*>(wf + (size_t)f * 1024 + l * 8);
    lo = *reinterpret_cast<const short8*>(wf + (size_t)f * 1024 + 512 + l * 8);
}

__global__ __launch_bounds__(BLOCK, 4)
void mvp_mfma(const float* __restrict__ src, const float* __restrict__ tgt,
              const float* __restrict__ feat,
              const unsigned short* __restrict__ wf,
              float* __restrict__ out)
{
    __shared__ __align__(16) unsigned short xh_hi[10*768], xh_lo[10*768];   // x; h2 aliased
    __shared__ __align__(16) unsigned short h1_hi[16*768], h1_lo[16*768];
    // total 79,872 B -> 2 blocks/CU

    const int tid = threadIdx.x;
    const int w   = tid >> 6;                    // 8 waves
    const int l   = tid & 63;
    const int b   = blockIdx.x >> 10;            // 1024 blocks per batch
    const int n0  = (blockIdx.x & 1023) << 5;    // 32 points

    // ================= staging =================
    if (tid < 96) {                               // zero pad fr 9 (ci 72..79)
        const int o = (9*96 + tid) * 8;
        const short8 z = {0,0,0,0,0,0,0,0};
        *reinterpret_cast<short8*>(&xh_hi[o]) = z;
        *reinterpret_cast<short8*>(&xh_lo[o]) = z;
    } else if (tid < 192) {                       // zero pad fr 8 pos 4..7 (ci 68..71)
        const int o = (8*96 + (tid - 96)) * 8 + 4;
        const short4v z = {0,0,0,0};
        *reinterpret_cast<short4v*>(&xh_hi[o]) = z;
        *reinterpret_cast<short4v*>(&xh_lo[o]) = z;
    }
    // feature -> ci 0..63: fr = c>>3, pos = c&7
#pragma unroll
    for (int it = 0; it < 4; ++it) {
        const int idx = tid + it * BLOCK;
        const int c = idx >> 5, p = idx & 31;
        const float4 f = *reinterpret_cast<const float4*>(
            feat + ((size_t)(b*C_ + c) * N_ + (n0 + p)) * K_);
        const float v[3] = {f.x, f.y, f.z};
#pragma unroll
        for (int k = 0; k < 3; ++k) {
            short hi, lo; bf16split(v[k], hi, lo);
            const int off = ((c >> 3)*96 + k*32 + p)*8 + (c & 7);
            xh_hi[off] = (unsigned short)hi; xh_lo[off] = (unsigned short)lo;
        }
    }
    // relation -> ci 64..67 (fr 8 pos 0..3)
    if (tid < 96) {
        const int p = tid & 31, k = tid >> 5;
        const int n = n0 + p;
        float d[4];
        d[0] = src[((size_t)(b*3+0)*N_ + n)*K_ + k] - tgt[(size_t)(b*3+0)*N_ + n];
        d[1] = src[((size_t)(b*3+1)*N_ + n)*K_ + k] - tgt[(size_t)(b*3+1)*N_ + n];
        d[2] = src[((size_t)(b*3+2)*N_ + n)*K_ + k] - tgt[(size_t)(b*3+2)*N_ + n];
        d[3] = d[0]*d[0] + d[1]*d[1] + d[2]*d[2];
        const int base = (8*96 + k*32 + p)*8;
#pragma unroll
        for (int j = 0; j < 4; ++j) {
            short hi, lo; bf16split(d[j], hi, lo);
            xh_hi[base + j] = (unsigned short)hi;
            xh_lo[base + j] = (unsigned short)lo;
        }
    }
    __syncthreads();

    const int hi32 = l >> 5, c32 = l & 31;       // 32x32 fragment coords
    const int lq = l >> 4, lr = l & 15, rq = lq << 2;  // 16x16 fragment coords
    const float* fb = reinterpret_cast<const float*>(wf + BIAS_OFF);

    // ================= L1: 68 -> 128 (32x32, 12 tiles: w then 8+w for w<4) ==
    {
        const int npass = (w < 4) ? 2 : 1;
        for (int pass = 0; pass < npass; ++pass) {
            const int t = pass ? (8 + w) : w;
            const int m = t / 3, n = t % 3;
            short8 ah[5], al[5];
#pragma unroll
            for (int ks = 0; ks < 5; ++ks) ldfrag(wf, m*5 + ks, l, ah[ks], al[ks]);
            f32x16 acc;
#pragma unroll
            for (int j = 0; j < 16; ++j) acc[j] = 0.0f;
#pragma unroll
            for (int ks = 0; ks < 5; ++ks) {
                const int so = ((ks*2 + hi32)*96 + n*32 + c32)*8;
                const short8 bh = *reinterpret_cast<const short8*>(&xh_hi[so]);
                const short8 bl = *reinterpret_cast<const short8*>(&xh_lo[so]);
                acc = mm32(ah[ks], bh, acc);
                acc = mm32(al[ks], bh, acc);
                acc = mm32(ah[ks], bl, acc);
            }
            // epilogue: rows = m*32 + 8g + 4*hi32 + rr
#pragma unroll
            for (int g = 0; g < 4; ++g) {
                const int co0 = m*32 + 8*g + 4*hi32;
                const float4 bb = *reinterpret_cast<const float4*>(fb + co0);
                const float bbv[4] = {bb.x, bb.y, bb.z, bb.w};
                short4v h4, l4;
#pragma unroll
                for (int r = 0; r < 4; ++r) {
                    const float v = fmaxf(acc[g*4 + r] + bbv[r], 0.0f);
                    short hh, ll; bf16split(v, hh, ll);
                    h4[r] = hh; l4[r] = ll;
                }
                const int so = ((m*4 + g)*96 + n*32 + c32)*8 + 4*hi32;
                *reinterpret_cast<short4v*>(&h1_hi[so]) = h4;
                *reinterpret_cast<short4v*>(&h1_lo[so]) = l4;
            }
        }
    }
    __syncthreads();

    // ================= L2: 128 -> 64 (32x32, 6 tiles over waves 0..5) =======
    if (w < 6) {
        const int m = w / 3, n = w % 3;
        short8 ah[8], al[8];
#pragma unroll
        for (int ks = 0; ks < 8; ++ks) ldfrag(wf, 20 + m*8 + ks, l, ah[ks], al[ks]);
        f32x16 acc;
#pragma unroll
        for (int j = 0; j < 16; ++j) acc[j] = 0.0f;
#pragma unroll
        for (int ks = 0; ks < 8; ++ks) {
            const int so = ((ks*2 + hi32)*96 + n*32 + c32)*8;
            const short8 bh = *reinterpret_cast<const short8*>(&h1_hi[so]);
            const short8 bl = *reinterpret_cast<const short8*>(&h1_lo[so]);
            acc = mm32(ah[ks], bh, acc);
            acc = mm32(al[ks], bh, acc);
            acc = mm32(ah[ks], bl, acc);
        }
        // h2 (aliased onto xh) with fr-stride 776
#pragma unroll
        for (int g = 0; g < 4; ++g) {
            const int co0 = m*32 + 8*g + 4*hi32;
            const float4 bb = *reinterpret_cast<const float4*>(fb + 128 + co0);
            const float bbv[4] = {bb.x, bb.y, bb.z, bb.w};
            short4v h4, l4;
#pragma unroll
            for (int r = 0; r < 4; ++r) {
                const float v = fmaxf(acc[g*4 + r] + bbv[r], 0.0f);
                short hh, ll; bf16split(v, hh, ll);
                h4[r] = hh; l4[r] = ll;
            }
            const int so = (m*4 + g)*H2STR + (n*32 + c32)*8 + 4*hi32;
            *reinterpret_cast<short4v*>(&xh_hi[so]) = h4;
            *reinterpret_cast<short4v*>(&xh_lo[so]) = l4;
        }
    }
    __syncthreads();

    // ================= L3: 64 -> 64 (16x16), relu + neighbor-sum + store ====
    {
        const int m = w >> 1, hh = w & 1;
        short8 ah[2], al[2];
#pragma unroll
        for (int ks = 0; ks < 2; ++ks) ldfrag(wf, 36 + m*2 + ks, l, ah[ks], al[ks]);
        f32x4 acc3[3] = {f32x4{0,0,0,0}, f32x4{0,0,0,0}, f32x4{0,0,0,0}};
#pragma unroll
        for (int ks = 0; ks < 2; ++ks) {
#pragma unroll
            for (int t = 0; t < 3; ++t) {          // t = neighbor k
                const int so = (ks*4 + lq)*H2STR + (t*32 + hh*16 + lr)*8;
                const short8 bh = *reinterpret_cast<const short8*>(&xh_hi[so]);
                const short8 bl = *reinterpret_cast<const short8*>(&xh_lo[so]);
                acc3[t] = mm16(ah[ks], bh, acc3[t]);
                acc3[t] = mm16(al[ks], bh, acc3[t]);
                acc3[t] = mm16(ah[ks], bl, acc3[t]);
            }
        }
        const int co0 = m*16 + rq;
        const float4 bb = *reinterpret_cast<const float4*>(fb + 192 + co0);
        const float bbv[4] = {bb.x, bb.y, bb.z, bb.w};
#pragma unroll
        for (int r = 0; r < 4; ++r) {
            float s = 0.0f;
#pragma unroll
            for (int t = 0; t < 3; ++t) s += fmaxf(acc3[t][r] + bbv[r], 0.0f);
            out[(size_t)(b*64 + co0 + r) * N_ + n0 + hh*16 + lr] = s;
        }
    }
}

extern "C" void kernel_launch(void* const* d_in, const int* in_sizes, int n_in,
                              void* d_out, int out_size, void* d_ws, size_t ws_size,
                              hipStream_t stream) {
    const float* src  = (const float*)d_in[0];
    const float* tgt  = (const float*)d_in[1];
    const float* feat = (const float*)d_in[2];
    const float* W1 = (const float*)d_in[3];
    const float* b1 = (const float*)d_in[4];
    const float* g1 = (const float*)d_in[5];
    const float* be1= (const float*)d_in[6];
    const float* W2 = (const float*)d_in[7];
    const float* b2 = (const float*)d_in[8];
    const float* g2 = (const float*)d_in[9];
    const float* be2= (const float*)d_in[10];
    const float* W3 = (const float*)d_in[11];
    const float* b3 = (const float*)d_in[12];
    const float* g3 = (const float*)d_in[13];
    const float* be3= (const float*)d_in[14];
    float* out = (float*)d_out;
    unsigned short* wfrag = (unsigned short*)d_ws;   // ~89 KB used

    prep_wfrags<<<12, 256, 0, stream>>>(W1, g1, b1, be1, W2, g2, b2, be2,
                                        W3, g3, b3, be3, wfrag);

    const int grid = B_ * (N_ / P_);  // 4096 blocks, 2 resident per CU
    mvp_mfma<<<grid, BLOCK, 0, stream>>>(src, tgt, feat, wfrag, out);
}

// Round 10
// 143.329 us; speedup vs baseline: 1.2983x; 1.1137x over previous
//
#include <hip/hip_runtime.h>
#include <math.h>

typedef __attribute__((ext_vector_type(8))) short short8;
typedef __attribute__((ext_vector_type(4))) short short4v;
typedef __attribute__((ext_vector_type(4))) float f32x4;
typedef __attribute__((ext_vector_type(16))) float f32x16;
typedef _Float16 half8 __attribute__((ext_vector_type(8)));

constexpr int BLOCK = 512;
constexpr int B_ = 4, C_ = 64, N_ = 32768, K_ = 16;
constexpr int P_ = 32;            // points per block -> 96 cols (col = k*32 + p)
// wf: 20 bf16 frags (L1: 4m x 5ks) + 16 f16 frags (L2: 2m x 8ks)
//     + 8 f16 frags (L3: 4m x 2ks), each 1024 shorts (hi 512 | lo 512), + 256 bias floats
constexpr int NFRAG = 44;
constexpr int BIAS_OFF = NFRAG * 1024;   // shorts

// x LDS: [9 fr][96 col][8] bf16 (hi+lo), fr = ci>>3 (ci 64..71 in fr8, 68..71 zero)
// + 8-short broadcast-zero pad at ZOFF (read by L1 ks=4 upper half)
constexpr int ZOFF = 9 * 768;            // 6912
constexpr int XSZ  = 6920;
// h1 LDS: [16 fr][96][8] f16 single. h2 aliased onto xa_hi, fr-stride 776 (f16 single).
constexpr int H2STR = 776;

// round-to-nearest-even split: f = hi_bf16 + lo_bf16 (+O(2^-17 rel))
__device__ __forceinline__ void bf16split(float f, short &hi, short &lo) {
    unsigned u  = __builtin_bit_cast(unsigned, f);
    unsigned hb = (u + 0x7FFFu + ((u >> 16) & 1u)) & 0xFFFF0000u;
    float hf    = __builtin_bit_cast(float, hb);
    hi = (short)(hb >> 16);
    float lf    = f - hf;                       // exact
    unsigned ul = __builtin_bit_cast(unsigned, lf);
    lo = (short)((ul + 0x7FFFu + ((ul >> 16) & 1u)) >> 16);
}

__device__ __forceinline__ short f16bits(float v) {
    return (short)__builtin_bit_cast(unsigned short, (_Float16)v);
}

__device__ __forceinline__ f32x16 mm32b(short8 a, short8 b, f32x16 c) {
    return __builtin_amdgcn_mfma_f32_32x32x16_bf16(a, b, c, 0, 0, 0);
}
__device__ __forceinline__ f32x16 mm32h(half8 a, half8 b, f32x16 c) {
    return __builtin_amdgcn_mfma_f32_32x32x16_f16(a, b, c, 0, 0, 0);
}
__device__ __forceinline__ f32x4 mm16h(half8 a, half8 b, f32x4 c) {
    return __builtin_amdgcn_mfma_f32_16x16x32_f16(a, b, c, 0, 0, 0);
}

// ---------------- prologue: BN-fold + split weights + fold biases ----------
__global__ void prep_wfrags(const float* __restrict__ W1, const float* __restrict__ g1,
                            const float* __restrict__ b1, const float* __restrict__ be1,
                            const float* __restrict__ W2, const float* __restrict__ g2,
                            const float* __restrict__ b2, const float* __restrict__ be2,
                            const float* __restrict__ W3, const float* __restrict__ g3,
                            const float* __restrict__ b3, const float* __restrict__ be3,
                            unsigned short* __restrict__ wf)
{
    const int gid = blockIdx.x * 256 + threadIdx.x;
    const float RS = 1.0f / sqrtf(1.0f + 1e-5f);
    const int NT = NFRAG * 64;                   // 2816 fragment lanes
    if (gid < NT) {
        const int f = gid >> 6, l = gid & 63;
        const float *W, *g; int CI, co, kb;
        if (f < 20)      { W = W1; g = g1; CI = 68;
                           co = (f / 5) * 32 + (l & 31);        kb = (f % 5) * 16 + (l >> 5) * 8; }
        else if (f < 36) { W = W2; g = g2; CI = 128;
                           co = ((f - 20) / 8) * 32 + (l & 31); kb = ((f - 20) % 8) * 16 + (l >> 5) * 8; }
        else             { W = W3; g = g3; CI = 64;
                           co = ((f - 36) / 2) * 16 + (l & 15); kb = ((f - 36) % 2) * 32 + (l >> 4) * 8; }
        const float gs = g[co] * RS;
        short8 h8, l8;
#pragma unroll
        for (int j = 0; j < 8; ++j) {
            const int k = kb + j;
            const float w = (k < CI) ? W[(size_t)co * CI + k] * gs : 0.0f;
            short hi, lo;
            if (f < 20) {
                bf16split(w, hi, lo);
            } else {                             // f16 hi/lo split
                _Float16 hf = (_Float16)w;
                hi = (short)__builtin_bit_cast(unsigned short, hf);
                lo = f16bits(w - (float)hf);
            }
            h8[j] = hi; l8[j] = lo;
        }
        *reinterpret_cast<short8*>(wf + (size_t)f * 1024 + l * 8)       = h8;
        *reinterpret_cast<short8*>(wf + (size_t)f * 1024 + 512 + l * 8) = l8;
    } else if (gid < NT + 256) {
        const int c = gid - NT;
        float* fb = reinterpret_cast<float*>(wf + BIAS_OFF);
        if (c < 128)      fb[c] = b1[c] * (g1[c] * RS) + be1[c];
        else if (c < 192) { const int q = c - 128; fb[c] = b2[q] * (g2[q] * RS) + be2[q]; }
        else              { const int q = c - 192; fb[c] = b3[q] * (g3[q] * RS) + be3[q]; }
    }
}

__device__ __forceinline__ void ldfrag(const unsigned short* __restrict__ wf,
                                       int f, int l, short8 &h, short8 &lo) {
    h  = *reinterpret_cast<const short8*>(wf + (size_t)f * 1024 + l * 8);
    lo = *reinterpret_cast<const short8*>(wf + (size_t)f * 1024 + 512 + l * 8);
}

__global__ __launch_bounds__(BLOCK, 6)
void mvp_mfma(const float* __restrict__ src, const float* __restrict__ tgt,
              const float* __restrict__ feat,
              const unsigned short* __restrict__ wf,
              float* __restrict__ out)
{
    __shared__ __align__(16) unsigned short xa_hi[XSZ], xa_lo[XSZ];  // 13.84 KB x2 (h2 aliases xa_hi)
    __shared__ __align__(16) unsigned short h1f[16*768];             // 24.58 KB (f16)
    // total 52,256 B -> 3 blocks/CU

    const int tid = threadIdx.x;
    const int w   = tid >> 6;                    // 8 waves
    const int l   = tid & 63;
    const int b   = blockIdx.x >> 10;            // 1024 blocks per batch
    const int n0  = (blockIdx.x & 1023) << 5;    // 32 points

    unsigned short* h2f = xa_hi;                 // aliased (x dead after L1)

    // ================= staging =================
    if (tid < 96) {                              // zero x fr8 pos 4..7 (ci 68..71)
        const int o = (8*96 + tid) * 8 + 4;
        const short4v z = {0,0,0,0};
        *reinterpret_cast<short4v*>(&xa_hi[o]) = z;
        *reinterpret_cast<short4v*>(&xa_lo[o]) = z;
    } else if (tid < 98) {                       // zero broadcast pad
        const short8 z = {0,0,0,0,0,0,0,0};
        *reinterpret_cast<short8*>((tid == 96 ? xa_hi : xa_lo) + ZOFF) = z;
    }
    // feature -> ci 0..63: fr = c>>3, pos = c&7
#pragma unroll
    for (int it = 0; it < 4; ++it) {
        const int idx = tid + it * BLOCK;
        const int c = idx >> 5, p = idx & 31;
        const float4 f = *reinterpret_cast<const float4*>(
            feat + ((size_t)(b*C_ + c) * N_ + (n0 + p)) * K_);
        const float v[3] = {f.x, f.y, f.z};
#pragma unroll
        for (int k = 0; k < 3; ++k) {
            short hi, lo; bf16split(v[k], hi, lo);
            const int off = ((c >> 3)*96 + k*32 + p)*8 + (c & 7);
            xa_hi[off] = (unsigned short)hi; xa_lo[off] = (unsigned short)lo;
        }
    }
    // relation -> ci 64..67 (fr 8 pos 0..3)
    if (tid < 96) {
        const int p = tid & 31, k = tid >> 5;
        const int n = n0 + p;
        float d[4];
        d[0] = src[((size_t)(b*3+0)*N_ + n)*K_ + k] - tgt[(size_t)(b*3+0)*N_ + n];
        d[1] = src[((size_t)(b*3+1)*N_ + n)*K_ + k] - tgt[(size_t)(b*3+1)*N_ + n];
        d[2] = src[((size_t)(b*3+2)*N_ + n)*K_ + k] - tgt[(size_t)(b*3+2)*N_ + n];
        d[3] = d[0]*d[0] + d[1]*d[1] + d[2]*d[2];
        const int base = (8*96 + k*32 + p)*8;
#pragma unroll
        for (int j = 0; j < 4; ++j) {
            short hi, lo; bf16split(d[j], hi, lo);
            xa_hi[base + j] = (unsigned short)hi;
            xa_lo[base + j] = (unsigned short)lo;
        }
    }
    __syncthreads();

    const int hi32 = l >> 5, c32 = l & 31;       // 32x32 fragment coords
    const int lq = l >> 4, lr = l & 15, rq = lq << 2;  // 16x16 fragment coords
    const float* fb = reinterpret_cast<const float*>(wf + BIAS_OFF);

    // ================= L1: 68 -> 128 (bf16 32x32, 12 tiles) =================
    {
        const int npass = (w < 4) ? 2 : 1;
        for (int pass = 0; pass < npass; ++pass) {
            const int t = pass ? (8 + w) : w;
            const int m = t / 3, n = t % 3;
            const int col = n*32 + c32;
            short8 ah[5], al[5];
#pragma unroll
            for (int ks = 0; ks < 5; ++ks) ldfrag(wf, m*5 + ks, l, ah[ks], al[ks]);
            f32x16 acc;
#pragma unroll
            for (int j = 0; j < 16; ++j) acc[j] = 0.0f;
#pragma unroll
            for (int ks = 0; ks < 4; ++ks) {
                const int so = ((ks*2 + hi32)*96 + col)*8;
                const short8 bh = *reinterpret_cast<const short8*>(&xa_hi[so]);
                const short8 bl = *reinterpret_cast<const short8*>(&xa_lo[so]);
                acc = mm32b(ah[ks], bh, acc);
                acc = mm32b(al[ks], bh, acc);
                acc = mm32b(ah[ks], bl, acc);
            }
            {   // ks = 4: ci 64..79; upper half (k 8..15) reads broadcast zero
                const int so = hi32 ? ZOFF : (8*96 + col)*8;
                const short8 bh = *reinterpret_cast<const short8*>(&xa_hi[so]);
                const short8 bl = *reinterpret_cast<const short8*>(&xa_lo[so]);
                acc = mm32b(ah[4], bh, acc);
                acc = mm32b(al[4], bh, acc);
                acc = mm32b(ah[4], bl, acc);
            }
            // epilogue -> h1 as single f16
#pragma unroll
            for (int g = 0; g < 4; ++g) {
                const int co0 = m*32 + 8*g + 4*hi32;
                const float4 bb = *reinterpret_cast<const float4*>(fb + co0);
                const float bbv[4] = {bb.x, bb.y, bb.z, bb.w};
                short4v h4;
#pragma unroll
                for (int r = 0; r < 4; ++r)
                    h4[r] = f16bits(fmaxf(acc[g*4 + r] + bbv[r], 0.0f));
                const int so = ((m*4 + g)*96 + col)*8 + 4*hi32;
                *reinterpret_cast<short4v*>(&h1f[so]) = h4;
            }
        }
    }
    __syncthreads();

    // ================= L2: 128 -> 64 (f16 32x32, 6 tiles, waves 0..5) =======
    if (w < 6) {
        const int m = w / 3, n = w % 3;
        const int col = n*32 + c32;
        f32x16 acc;
#pragma unroll
        for (int j = 0; j < 16; ++j) acc[j] = 0.0f;
#pragma unroll
        for (int ks = 0; ks < 8; ++ks) {
            short8 ahs, als;
            ldfrag(wf, 20 + m*8 + ks, l, ahs, als);
            const int so = ((ks*2 + hi32)*96 + col)*8;
            const half8 bh = __builtin_bit_cast(half8,
                *reinterpret_cast<const short8*>(&h1f[so]));
            acc = mm32h(__builtin_bit_cast(half8, ahs), bh, acc);
            acc = mm32h(__builtin_bit_cast(half8, als), bh, acc);
        }
        // h2 (aliased onto xa_hi) with fr-stride 776, single f16
#pragma unroll
        for (int g = 0; g < 4; ++g) {
            const int co0 = m*32 + 8*g + 4*hi32;
            const float4 bb = *reinterpret_cast<const float4*>(fb + 128 + co0);
            const float bbv[4] = {bb.x, bb.y, bb.z, bb.w};
            short4v h4;
#pragma unroll
            for (int r = 0; r < 4; ++r)
                h4[r] = f16bits(fmaxf(acc[g*4 + r] + bbv[r], 0.0f));
            const int so = (m*4 + g)*H2STR + col*8 + 4*hi32;
            *reinterpret_cast<short4v*>(&h2f[so]) = h4;
        }
    }
    __syncthreads();

    // ================= L3: 64 -> 64 (f16 16x16), relu + neighbor-sum + store =
    {
        const int m = w >> 1, hh = w & 1;
        short8 ah[2], al[2];
#pragma unroll
        for (int ks = 0; ks < 2; ++ks) ldfrag(wf, 36 + m*2 + ks, l, ah[ks], al[ks]);
        f32x4 acc3[3] = {f32x4{0,0,0,0}, f32x4{0,0,0,0}, f32x4{0,0,0,0}};
#pragma unroll
        for (int ks = 0; ks < 2; ++ks) {
#pragma unroll
            for (int t = 0; t < 3; ++t) {          // t = neighbor k
                const int so = (ks*4 + lq)*H2STR + (t*32 + hh*16 + lr)*8;
                const half8 bh = __builtin_bit_cast(half8,
                    *reinterpret_cast<const short8*>(&h2f[so]));
                acc3[t] = mm16h(__builtin_bit_cast(half8, ah[ks]), bh, acc3[t]);
                acc3[t] = mm16h(__builtin_bit_cast(half8, al[ks]), bh, acc3[t]);
            }
        }
        const int co0 = m*16 + rq;
        const float4 bb = *reinterpret_cast<const float4*>(fb + 192 + co0);
        const float bbv[4] = {bb.x, bb.y, bb.z, bb.w};
#pragma unroll
        for (int r = 0; r < 4; ++r) {
            float s = 0.0f;
#pragma unroll
            for (int t = 0; t < 3; ++t) s += fmaxf(acc3[t][r] + bbv[r], 0.0f);
            out[(size_t)(b*64 + co0 + r) * N_ + n0 + hh*16 + lr] = s;
        }
    }
}

extern "C" void kernel_launch(void* const* d_in, const int* in_sizes, int n_in,
                              void* d_out, int out_size, void* d_ws, size_t ws_size,
                              hipStream_t stream) {
    const float* src  = (const float*)d_in[0];
    const float* tgt  = (const float*)d_in[1];
    const float* feat = (const float*)d_in[2];
    const float* W1 = (const float*)d_in[3];
    const float* b1 = (const float*)d_in[4];
    const float* g1 = (const float*)d_in[5];
    const float* be1= (const float*)d_in[6];
    const float* W2 = (const float*)d_in[7];
    const float* b2 = (const float*)d_in[8];
    const float* g2 = (const float*)d_in[9];
    const float* be2= (const float*)d_in[10];
    const float* W3 = (const float*)d_in[11];
    const float* b3 = (const float*)d_in[12];
    const float* g3 = (const float*)d_in[13];
    const float* be3= (const float*)d_in[14];
    float* out = (float*)d_out;
    unsigned short* wfrag = (unsigned short*)d_ws;   // ~91 KB used

    prep_wfrags<<<12, 256, 0, stream>>>(W1, g1, b1, be1, W2, g2, b2, be2,
                                        W3, g3, b3, be3, wfrag);

    const int grid = B_ * (N_ / P_);  // 4096 blocks, 3 resident per CU
    mvp_mfma<<<grid, BLOCK, 0, stream>>>(src, tgt, feat, wfrag, out);
}